// Round 1
// baseline (1641.981 us; speedup 1.0000x reference)
//
#include <hip/hip_runtime.h>
#include <cstdint>
#include <cstddef>

// Problem constants (GCMCLayer_70549132804177)
constexpr int kR   = 5;
constexpr int kNU  = 100000;
constexpr int kNM  = 100000;
constexpr int kE   = 1000000;
constexpr int kIN  = 64;
constexpr int kMSG = 80;
constexpr int kOUT = 64;
constexpr int kBAS = 4;
constexpr int kMPR = 16;   // kMSG / kR

constexpr int kN          = 100000;            // nodes per side (NU == NM)
constexpr int kKeysPerDir = kN * kR;           // 500000
constexpr int kNKEY       = 2 * kKeysPerDir;   // 1000000
constexpr int kCHUNK      = 2048;              // keys per scan block
constexpr int kSCANBLK    = (kNKEY + kCHUNK - 1) / kCHUNK;  // 489
constexpr unsigned kEdges = (unsigned)kR * (unsigned)kE;     // 5M per direction

// ---------------------------------------------------------------------------
// Kernel 1: per-node message precompute (unchanged from previous round).
//   W[r,i,k] = sum_b att[r,b]*basis[b,i,k] (LDS, broadcast-read)
//   msg[r,node,k] = (sum_i feat[node,i]*W[r,i,k]) * cj[node]
// ---------------------------------------------------------------------------
__global__ __launch_bounds__(256) void gcmc_msg(
    const float* __restrict__ feat, const float* __restrict__ cj,
    const float* __restrict__ att,  const float* __restrict__ basis,
    float* __restrict__ msg, int n_nodes)
{
    __shared__ float Wl[kR * kIN * kMPR];   // [r][i][k], k contiguous (20 KB)
    const int tid = threadIdx.x;
    for (int idx = tid; idx < kR * kIN * kMPR; idx += 256) {
        const int r   = idx >> 10;          // / (64*16)
        const int rem = idx & 1023;
        const int i   = rem >> 4;
        const int k   = rem & 15;
        float s = 0.f;
#pragma unroll
        for (int b = 0; b < kBAS; ++b)
            s += att[r * kBAS + b] * basis[(b * kIN + i) * kMPR + k];
        Wl[idx] = s;
    }
    __syncthreads();

    const int node = blockIdx.x * 256 + tid;
    if (node >= n_nodes) return;

    float f[kIN];
    const float4* fp = reinterpret_cast<const float4*>(feat + (size_t)node * kIN);
#pragma unroll
    for (int i = 0; i < kIN / 4; ++i) {
        float4 v = fp[i];
        f[4 * i + 0] = v.x; f[4 * i + 1] = v.y;
        f[4 * i + 2] = v.z; f[4 * i + 3] = v.w;
    }
    const float c = cj[node];
    const float4* W4 = reinterpret_cast<const float4*>(Wl);
    float4* mout = reinterpret_cast<float4*>(msg);

    for (int r = 0; r < kR; ++r) {          // runtime r: only LDS/addr index
#pragma unroll
        for (int kg = 0; kg < kMPR / 4; ++kg) {
            float4 a = make_float4(0.f, 0.f, 0.f, 0.f);
#pragma unroll
            for (int i = 0; i < kIN; ++i) {            // FULL unroll: f[i] static
                float4 w = W4[(r * kIN + i) * (kMPR / 4) + kg];  // LDS broadcast
                a.x += f[i] * w.x; a.y += f[i] * w.y;
                a.z += f[i] * w.z; a.w += f[i] * w.w;
            }
            a.x *= c; a.y *= c; a.z *= c; a.w *= c;
            mout[((size_t)r * n_nodes + node) * (kMPR / 4) + kg] = a;
        }
    }
}

// ---------------------------------------------------------------------------
// Kernel 2a: histogram of edges into (dst*5 + r) bins. counts is pre-offset
// by direction. 1 atomic per edge (was 16 per edge in the scatter design).
// ---------------------------------------------------------------------------
__global__ __launch_bounds__(256) void gcmc_hist(
    const int* __restrict__ dsts, uint32_t* __restrict__ counts)
{
    const unsigned gid = blockIdx.x * 256u + threadIdx.x;
    if (gid >= kEdges) return;
    const unsigned r = gid / (unsigned)kE;       // magic-mul
    const int d = dsts[gid];
    atomicAdd(&counts[(unsigned)d * kR + r], 1u);
}

// ---------------------------------------------------------------------------
// Kernel 2b/2c/2d: exclusive scan over kNKEY counts -> starts (+ cursor copy).
// ---------------------------------------------------------------------------
__global__ __launch_bounds__(256) void scan_blocksum(
    const uint32_t* __restrict__ counts, uint32_t* __restrict__ bsum)
{
    __shared__ uint32_t sh[256];
    const int t = threadIdx.x;
    const int base = blockIdx.x * kCHUNK;
    uint32_t s = 0;
    for (int i = t; i < kCHUNK; i += 256) {
        const int idx = base + i;
        if (idx < kNKEY) s += counts[idx];
    }
    sh[t] = s; __syncthreads();
    for (int off = 128; off > 0; off >>= 1) {
        if (t < off) sh[t] += sh[t + off];
        __syncthreads();
    }
    if (t == 0) bsum[blockIdx.x] = sh[0];
}

__global__ __launch_bounds__(512) void scan_bsum(
    const uint32_t* __restrict__ bsum, uint32_t* __restrict__ boff,
    uint32_t* __restrict__ starts)
{
    __shared__ uint32_t sh[512];
    const int t = threadIdx.x;
    const uint32_t mine = (t < kSCANBLK) ? bsum[t] : 0u;
    sh[t] = mine;
    __syncthreads();
    for (int off = 1; off < 512; off <<= 1) {     // Hillis-Steele inclusive
        const uint32_t v = (t >= off) ? sh[t - off] : 0u;
        __syncthreads();
        sh[t] += v;
        __syncthreads();
    }
    if (t < kSCANBLK) boff[t] = sh[t] - mine;     // exclusive block offset
    if (t == 511) starts[kNKEY] = sh[511];        // grand total (= 10M)
}

__global__ __launch_bounds__(256) void scan_final(
    const uint32_t* __restrict__ counts, const uint32_t* __restrict__ boff,
    uint32_t* __restrict__ starts, uint32_t* __restrict__ cursor)
{
    __shared__ uint32_t sh[256];
    const int t = threadIdx.x;
    const int base = blockIdx.x * kCHUNK + t * 8;
    uint32_t c[8];
    uint32_t s = 0;
#pragma unroll
    for (int i = 0; i < 8; ++i) {
        const int idx = base + i;
        c[i] = (idx < kNKEY) ? counts[idx] : 0u;
        s += c[i];
    }
    sh[t] = s; __syncthreads();
    for (int off = 1; off < 256; off <<= 1) {     // Hillis-Steele inclusive
        const uint32_t v = (t >= off) ? sh[t - off] : 0u;
        __syncthreads();
        sh[t] += v;
        __syncthreads();
    }
    uint32_t run = boff[blockIdx.x] + sh[t] - s;  // exclusive prefix
#pragma unroll
    for (int i = 0; i < 8; ++i) {
        const int idx = base + i;
        if (idx < kNKEY) { starts[idx] = run; cursor[idx] = run; }
        run += c[i];
    }
}

// ---------------------------------------------------------------------------
// Kernel 2e: placement — counting-sort scatter of src ids into per-(dst,r)
// segments. Record = src id only (r is encoded in the segment key).
// cursor is pre-offset by direction; positions are global into recs.
// ---------------------------------------------------------------------------
__global__ __launch_bounds__(256) void gcmc_place(
    const int* __restrict__ dsts, const int* __restrict__ srcs,
    uint32_t* __restrict__ cursor, uint32_t* __restrict__ recs)
{
    const unsigned gid = blockIdx.x * 256u + threadIdx.x;
    if (gid >= kEdges) return;
    const unsigned r = gid / (unsigned)kE;
    const unsigned d = (unsigned)dsts[gid];
    const unsigned s = (unsigned)srcs[gid];
    const unsigned pos = atomicAdd(&cursor[d * kR + r], 1u);
    recs[pos] = s;
}

// ---------------------------------------------------------------------------
// Kernel 3: atomic-free segmented gather + fused ci*relu*FC epilogue.
// One 16-lane group per destination node (lane = message column k).
// Walks the node's 5 per-r segments: one coalesced 64B msg line per record.
// Group then holds all 80 accumulated values -> FC done in-block via LDS.
// W is staged TRANSPOSED [j][o] so the per-lane float4 reads (o = 4*lane..)
// are 64 consecutive dwords across the group: conflict-free.
// ---------------------------------------------------------------------------
__global__ __launch_bounds__(256) void gcmc_gather_fc(
    const float* __restrict__ fu, const float* __restrict__ fi,
    const uint32_t* __restrict__ recs, const uint32_t* __restrict__ starts,
    const float* __restrict__ ci_user, const float* __restrict__ ci_movie,
    const float* __restrict__ fc_w, const float* __restrict__ fc_b,
    float* __restrict__ out_u, float* __restrict__ out_m)
{
    __shared__ float Wt[kMSG * kOUT];   // [j][o]  (20 KB)
    __shared__ float Bl[kOUT];
    __shared__ float Xs[16][kMSG];      // per-group x vector (5 KB)
    const int tid = threadIdx.x;
    for (int idx = tid; idx < kOUT * kMSG; idx += 256) {
        const int o = idx / kMSG;
        const int j = idx - o * kMSG;
        Wt[j * kOUT + o] = fc_w[idx];   // transpose on load
    }
    if (tid < kOUT) Bl[tid] = fc_b[tid];

    const int lane = tid & 15;
    const int grp  = tid >> 4;
    const int node = blockIdx.x * 16 + grp;      // 0..2*kN-1, grid exact
    const int dir  = node >= kN;                 // 0: dst=movie, 1: dst=user
    const int d    = dir ? node - kN : node;
    const float* msgb = dir ? fi : fu;
    const float* cip  = dir ? ci_user : ci_movie;
    float* outp       = dir ? out_u : out_m;
    const uint32_t base = (uint32_t)node * kR;   // = dir*500000 + d*5

    float acc[kR];
#pragma unroll
    for (int r = 0; r < kR; ++r) {               // static r -> acc in VGPRs
        uint32_t j  = starts[base + r];
        const uint32_t je = starts[base + r + 1];
        const float* plane = msgb + (size_t)r * kN * kMPR + lane;
        float a = 0.f;
        for (; j + 2 <= je; j += 2) {            // 2 gathers in flight
            const uint32_t s0 = recs[j];
            const uint32_t s1 = recs[j + 1];
            a += plane[(size_t)s0 * kMPR];
            a += plane[(size_t)s1 * kMPR];
        }
        if (j < je) a += plane[(size_t)recs[j] * kMPR];
        acc[r] = a;
    }

    const float c = cip[d];
#pragma unroll
    for (int r = 0; r < kR; ++r)
        Xs[grp][r * kMPR + lane] = fmaxf(acc[r] * c, 0.f);
    __syncthreads();                              // covers Wt/Bl preload too

    const float4* X4 = reinterpret_cast<const float4*>(&Xs[grp][0]);
    float4 a4 = reinterpret_cast<const float4*>(Bl)[lane];   // o = 4*lane..+3
#pragma unroll
    for (int jj = 0; jj < kMSG / 4; ++jj) {
        const float4 xv = X4[jj];                 // broadcast within group
        const float* Wr = &Wt[(jj * 4) * kOUT + lane * 4];
        const float4 w0 = *reinterpret_cast<const float4*>(Wr);
        const float4 w1 = *reinterpret_cast<const float4*>(Wr + kOUT);
        const float4 w2 = *reinterpret_cast<const float4*>(Wr + 2 * kOUT);
        const float4 w3 = *reinterpret_cast<const float4*>(Wr + 3 * kOUT);
        a4.x += xv.x * w0.x + xv.y * w1.x + xv.z * w2.x + xv.w * w3.x;
        a4.y += xv.x * w0.y + xv.y * w1.y + xv.z * w2.y + xv.w * w3.y;
        a4.z += xv.x * w0.z + xv.y * w1.z + xv.z * w2.z + xv.w * w3.z;
        a4.w += xv.x * w0.w + xv.y * w1.w + xv.z * w2.w + xv.w * w3.w;
    }
    *reinterpret_cast<float4*>(outp + (size_t)d * kOUT + lane * 4) = a4;
}

// ---------------------------------------------------------------------------
extern "C" void kernel_launch(void* const* d_in, const int* in_sizes, int n_in,
                              void* d_out, int out_size, void* d_ws, size_t ws_size,
                              hipStream_t stream) {
    const float* ufeat    = (const float*)d_in[0];
    const float* ifeat    = (const float*)d_in[1];
    const float* cj_user  = (const float*)d_in[2];
    const float* ci_user  = (const float*)d_in[3];
    const float* cj_movie = (const float*)d_in[4];
    const float* ci_movie = (const float*)d_in[5];
    const int*   edge_user  = (const int*)d_in[6];
    const int*   edge_movie = (const int*)d_in[7];
    const float* att   = (const float*)d_in[8];
    const float* basis = (const float*)d_in[9];
    const float* fc_w  = (const float*)d_in[10];
    const float* fc_b  = (const float*)d_in[11];

    float* out_u = (float*)d_out;                    // [NU][64]
    float* out_m = out_u + (size_t)kNU * kOUT;       // [NM][64]

    // Workspace layout:
    //   fu     [R][NU][16] f32 = 32 MB
    //   fi     [R][NM][16] f32 = 32 MB
    //   recs   [10M]       u32 = 40 MB   (sorted src ids, global positions)
    //   counts [1M]        u32 =  4 MB
    //   starts [1M+1]      u32 =  4 MB
    //   cursor [1M]        u32 =  4 MB
    //   bsum/boff [489]    u32 ~  4 KB
    // total ~116 MB
    float* fu = (float*)d_ws;
    float* fi = fu + (size_t)kR * kN * kMPR;
    uint32_t* recs   = (uint32_t*)(fi + (size_t)kR * kN * kMPR);
    uint32_t* counts = recs + (size_t)2 * kEdges;
    uint32_t* starts = counts + kNKEY;
    uint32_t* cursor = starts + kNKEY + 1;
    uint32_t* bsum   = cursor + kNKEY;
    uint32_t* boff   = bsum + kSCANBLK;

    hipMemsetAsync(counts, 0, (size_t)kNKEY * sizeof(uint32_t), stream);

    gcmc_msg<<<(kN + 255) / 256, 256, 0, stream>>>(ufeat, cj_user,  att, basis, fu, kN);
    gcmc_msg<<<(kN + 255) / 256, 256, 0, stream>>>(ifeat, cj_movie, att, basis, fi, kN);

    const int eblocks = (int)((kEdges + 255u) / 256u);   // 19532
    // dir 0: user -> movie (dst = movie); dir 1: movie -> user (dst = user)
    gcmc_hist<<<eblocks, 256, 0, stream>>>(edge_movie, counts);
    gcmc_hist<<<eblocks, 256, 0, stream>>>(edge_user,  counts + kKeysPerDir);

    scan_blocksum<<<kSCANBLK, 256, 0, stream>>>(counts, bsum);
    scan_bsum<<<1, 512, 0, stream>>>(bsum, boff, starts);
    scan_final<<<kSCANBLK, 256, 0, stream>>>(counts, boff, starts, cursor);

    gcmc_place<<<eblocks, 256, 0, stream>>>(edge_movie, edge_user, cursor, recs);
    gcmc_place<<<eblocks, 256, 0, stream>>>(edge_user, edge_movie, cursor + kKeysPerDir, recs);

    gcmc_gather_fc<<<(2 * kN) / 16, 256, 0, stream>>>(
        fu, fi, recs, starts, ci_user, ci_movie, fc_w, fc_b, out_u, out_m);
}

// Round 2
// 506.977 us; speedup vs baseline: 3.2388x; 3.2388x over previous
//
#include <hip/hip_runtime.h>
#include <cstdint>
#include <cstddef>

// Problem constants (GCMCLayer_70549132804177)
constexpr int kR   = 5;
constexpr int kNU  = 100000;
constexpr int kNM  = 100000;
constexpr int kE   = 1000000;
constexpr int kIN  = 64;
constexpr int kMSG = 80;
constexpr int kOUT = 64;
constexpr int kBAS = 4;
constexpr int kMPR = 16;   // kMSG / kR

constexpr int kN        = 100000;                  // nodes per side
constexpr int kNKEY     = 2 * kN * kR;             // 1,000,000 fine segments
constexpr unsigned kEdges = (unsigned)kR * (unsigned)kE;   // 5M per direction
constexpr unsigned kTotRecs = 2u * kEdges;         // 10M records

// Coarse bucketing: 512 dsts per bucket
constexpr int kNB        = (kN + 511) / 512;       // 196 buckets per direction
constexpr int kChunkE    = 4096;                   // edges per partition block
constexpr int kDirBlocks = (int)((kEdges + kChunkE - 1) / kChunkE);  // 1221
constexpr int kSegPerBkt = 512 * kR;               // 2560 fine segments/bucket

// ---------------------------------------------------------------------------
// Kernel 1: per-node message precompute (unchanged).
//   W[r,i,k] = sum_b att[r,b]*basis[b,i,k] (LDS, broadcast-read)
//   msg[r,node,k] = (sum_i feat[node,i]*W[r,i,k]) * cj[node]
// ---------------------------------------------------------------------------
__global__ __launch_bounds__(256) void gcmc_msg(
    const float* __restrict__ feat, const float* __restrict__ cj,
    const float* __restrict__ att,  const float* __restrict__ basis,
    float* __restrict__ msg, int n_nodes)
{
    __shared__ float Wl[kR * kIN * kMPR];   // [r][i][k], k contiguous (20 KB)
    const int tid = threadIdx.x;
    for (int idx = tid; idx < kR * kIN * kMPR; idx += 256) {
        const int r   = idx >> 10;
        const int rem = idx & 1023;
        const int i   = rem >> 4;
        const int k   = rem & 15;
        float s = 0.f;
#pragma unroll
        for (int b = 0; b < kBAS; ++b)
            s += att[r * kBAS + b] * basis[(b * kIN + i) * kMPR + k];
        Wl[idx] = s;
    }
    __syncthreads();

    const int node = blockIdx.x * 256 + tid;
    if (node >= n_nodes) return;

    float f[kIN];
    const float4* fp = reinterpret_cast<const float4*>(feat + (size_t)node * kIN);
#pragma unroll
    for (int i = 0; i < kIN / 4; ++i) {
        float4 v = fp[i];
        f[4 * i + 0] = v.x; f[4 * i + 1] = v.y;
        f[4 * i + 2] = v.z; f[4 * i + 3] = v.w;
    }
    const float c = cj[node];
    const float4* W4 = reinterpret_cast<const float4*>(Wl);
    float4* mout = reinterpret_cast<float4*>(msg);

    for (int r = 0; r < kR; ++r) {
#pragma unroll
        for (int kg = 0; kg < kMPR / 4; ++kg) {
            float4 a = make_float4(0.f, 0.f, 0.f, 0.f);
#pragma unroll
            for (int i = 0; i < kIN; ++i) {            // FULL unroll: f[i] static
                float4 w = W4[(r * kIN + i) * (kMPR / 4) + kg];
                a.x += f[i] * w.x; a.y += f[i] * w.y;
                a.z += f[i] * w.z; a.w += f[i] * w.w;
            }
            a.x *= c; a.y *= c; a.z *= c; a.w *= c;
            mout[((size_t)r * n_nodes + node) * (kMPR / 4) + kg] = a;
        }
    }
}

// ---------------------------------------------------------------------------
// Phase A: coarse bucket counts (LDS histogram, ~0.5M global atomics total).
// grid = 2*kDirBlocks; blocks >= kDirBlocks handle direction 1.
// dir 0: dst = movie; dir 1: dst = user.
// ---------------------------------------------------------------------------
__global__ __launch_bounds__(256) void gcmc_bucket_count(
    const int* __restrict__ dst0, const int* __restrict__ dst1,
    uint32_t* __restrict__ bucket_count)
{
    __shared__ uint32_t h[kNB];
    const int tid = threadIdx.x;
    const int dir = blockIdx.x >= kDirBlocks;
    const int blk = blockIdx.x - dir * kDirBlocks;
    const int* dsts = dir ? dst1 : dst0;
    for (int i = tid; i < kNB; i += 256) h[i] = 0;
    __syncthreads();
    const unsigned base = (unsigned)blk * kChunkE;
#pragma unroll
    for (int j = 0; j < kChunkE / 256; ++j) {
        const unsigned idx = base + j * 256u + tid;
        if (idx < kEdges) atomicAdd(&h[(unsigned)dsts[idx] >> 9], 1u);
    }
    __syncthreads();
    for (int i = tid; i < kNB; i += 256) {
        const uint32_t c = h[i];
        if (c) atomicAdd(&bucket_count[dir * kNB + i], c);
    }
}

// ---------------------------------------------------------------------------
// Phase B: exclusive scan of 392 bucket counts -> bucket_base, cursor.
// Also writes the starts[] sentinel.
// ---------------------------------------------------------------------------
__global__ __launch_bounds__(512) void gcmc_bucket_scan(
    const uint32_t* __restrict__ bucket_count,
    uint32_t* __restrict__ bucket_base, uint32_t* __restrict__ cursor,
    uint32_t* __restrict__ starts)
{
    __shared__ uint32_t sh[512];
    const int t = threadIdx.x;
    const uint32_t mine = (t < 2 * kNB) ? bucket_count[t] : 0u;
    sh[t] = mine; __syncthreads();
    for (int off = 1; off < 512; off <<= 1) {
        const uint32_t v = (t >= off) ? sh[t - off] : 0u;
        __syncthreads();
        sh[t] += v;
        __syncthreads();
    }
    if (t < 2 * kNB) { bucket_base[t] = sh[t] - mine; cursor[t] = sh[t] - mine; }
    if (t == 2 * kNB - 1) bucket_base[2 * kNB] = sh[t];
    if (t == 0) starts[kNKEY] = kTotRecs;
}

// ---------------------------------------------------------------------------
// Phase C: LDS-staged partition (multisplit). Each block takes 4096 edges,
// orders them by bucket in LDS, reserves per-bucket global ranges (1 atomic
// per bucket per block), then copies out CONTIGUOUS runs -> coalesced writes
// (avg 21 recs = 84 B per run vs 4 B random in the old gcmc_place).
// Packed record: src[0:16] | dst_local[17:25] | r[26:28].
// ---------------------------------------------------------------------------
__global__ __launch_bounds__(256) void gcmc_partition(
    const int* __restrict__ dst0, const int* __restrict__ src0,
    const int* __restrict__ dst1, const int* __restrict__ src1,
    uint32_t* __restrict__ cursor, uint32_t* __restrict__ bucket_recs)
{
    __shared__ uint32_t hist[kNB];
    __shared__ uint32_t excl[kNB];
    __shared__ uint32_t gbase[kNB];
    __shared__ uint32_t scanT[256];
    __shared__ uint32_t stage[kChunkE];     // 16 KB
    __shared__ uint8_t  sbkt[kChunkE];      // 4 KB
    const int tid = threadIdx.x;
    const int dir = blockIdx.x >= kDirBlocks;
    const int blk = blockIdx.x - dir * kDirBlocks;
    const int* dsts = dir ? dst1 : dst0;
    const int* srcs = dir ? src1 : src0;

    for (int i = tid; i < kNB; i += 256) hist[i] = 0;
    __syncthreads();

    const unsigned base = (unsigned)blk * kChunkE;
    uint32_t rec[16], bk[16], rk[16];
#pragma unroll
    for (int j = 0; j < 16; ++j) {
        const unsigned idx = base + j * 256u + tid;
        if (idx < kEdges) {
            const unsigned d = (unsigned)dsts[idx];
            const unsigned s = (unsigned)srcs[idx];
            const unsigned r = idx / (unsigned)kE;     // magic-mul
            rec[j] = s | ((d & 511u) << 17) | (r << 26);
            bk[j]  = d >> 9;
            rk[j]  = atomicAdd(&hist[bk[j]], 1u);      // local rank in bucket
        } else bk[j] = 0xFFFFFFFFu;
    }
    __syncthreads();

    const uint32_t c = (tid < kNB) ? hist[tid] : 0u;   // block-local count
    scanT[tid] = c; __syncthreads();
    for (int off = 1; off < 256; off <<= 1) {
        const uint32_t v = (tid >= off) ? scanT[tid - off] : 0u;
        __syncthreads();
        scanT[tid] += v;
        __syncthreads();
    }
    const uint32_t total = scanT[255];
    if (tid < kNB) {
        excl[tid]  = scanT[tid] - c;                   // LDS staging base
        gbase[tid] = c ? atomicAdd(&cursor[dir * kNB + tid], c) : 0u;
    }
    __syncthreads();

#pragma unroll
    for (int j = 0; j < 16; ++j) {
        if (bk[j] != 0xFFFFFFFFu) {
            const uint32_t p = excl[bk[j]] + rk[j];
            stage[p] = rec[j];
            sbkt[p]  = (uint8_t)bk[j];
        }
    }
    __syncthreads();

    for (unsigned p = tid; p < total; p += 256) {      // coalesced copy-out
        const uint32_t b = sbkt[p];
        bucket_recs[gbase[b] + (p - excl[b])] = stage[p];
    }
}

// ---------------------------------------------------------------------------
// Phase D: per-bucket fine sort. One block per (dir,bucket). Builds the
// 2560-segment histogram in LDS, scans, writes global starts[], then
// scatters records. The scatter targets a ~100 KB L2-resident region, so
// HBM only sees the clean 40 MB write-back (no line amplification).
// Output record: plane_idx = r*kN+src in [0:18] | r in [19:21].
// ---------------------------------------------------------------------------
__global__ __launch_bounds__(256) void gcmc_bucket_sort(
    const uint32_t* __restrict__ bucket_recs,
    const uint32_t* __restrict__ bucket_base,
    uint32_t* __restrict__ starts, uint32_t* __restrict__ recs)
{
    __shared__ uint32_t hist[kSegPerBkt];   // 10 KB
    __shared__ uint32_t scanT[256];
    const int tid = threadIdx.x;
    const int db  = blockIdx.x;                 // 0..2*kNB-1
    const int dir = db >= kNB;
    const int bl  = db - dir * kNB;
    const uint32_t gb0 = bucket_base[db], gb1 = bucket_base[db + 1];
    const int dstBase = bl << 9;
    const int ndst = (kN - dstBase < 512) ? (kN - dstBase) : 512;
    const int nseg = ndst * kR;

    for (int i = tid; i < kSegPerBkt; i += 256) hist[i] = 0;
    __syncthreads();

    for (uint32_t i = gb0 + tid; i < gb1; i += 256) {
        const uint32_t rec = bucket_recs[i];
        const uint32_t seg = ((rec >> 17) & 511u) * kR + (rec >> 26);
        atomicAdd(&hist[seg], 1u);
    }
    __syncthreads();

    // exclusive scan of 2560 = 256 threads x 10 consecutive
    uint32_t loc[10]; uint32_t s = 0;
#pragma unroll
    for (int q = 0; q < 10; ++q) { loc[q] = hist[tid * 10 + q]; s += loc[q]; }
    scanT[tid] = s; __syncthreads();
    for (int off = 1; off < 256; off <<= 1) {
        const uint32_t v = (tid >= off) ? scanT[tid - off] : 0u;
        __syncthreads();
        scanT[tid] += v;
        __syncthreads();
    }
    uint32_t run = gb0 + scanT[tid] - s;        // global exclusive prefix
#pragma unroll
    for (int q = 0; q < 10; ++q) { hist[tid * 10 + q] = run; run += loc[q]; }
    __syncthreads();

    const uint32_t keybase = (uint32_t)dir * (uint32_t)(kN * kR)
                           + (uint32_t)dstBase * kR;
    for (int sg = tid; sg < nseg; sg += 256) starts[keybase + sg] = hist[sg];
    __syncthreads();

    for (uint32_t i = gb0 + tid; i < gb1; i += 256) {
        const uint32_t rec = bucket_recs[i];
        const uint32_t r   = rec >> 26;
        const uint32_t seg = ((rec >> 17) & 511u) * kR + r;
        const uint32_t pos = atomicAdd(&hist[seg], 1u);
        recs[pos] = ((rec & 0x1FFFFu) + r * (uint32_t)kN) | (r << 19);
    }
}

// ---------------------------------------------------------------------------
// Kernel 3: atomic-free segmented gather + fused ci*relu*FC epilogue.
// One 16-lane group per destination node (lane = message column k).
// Unified walk over the node's 5 consecutive segments (r packed in record),
// 4-deep load pipelining, 5-way select accumulate.
// ---------------------------------------------------------------------------
__global__ __launch_bounds__(256) void gcmc_gather_fc(
    const float* __restrict__ fu,              // fi = fu + kR*kN*kMPR
    const uint32_t* __restrict__ recs, const uint32_t* __restrict__ starts,
    const float* __restrict__ ci_user, const float* __restrict__ ci_movie,
    const float* __restrict__ fc_w, const float* __restrict__ fc_b,
    float* __restrict__ out_u, float* __restrict__ out_m)
{
    __shared__ float Wt[kMSG * kOUT];   // [j][o]  (20 KB), transposed on load
    __shared__ float Bl[kOUT];
    __shared__ float Xs[16][kMSG];      // per-group x vector (5 KB)
    const int tid = threadIdx.x;
    for (int idx = tid; idx < kOUT * kMSG; idx += 256) {
        const int o = idx / kMSG;
        const int j = idx - o * kMSG;
        Wt[j * kOUT + o] = fc_w[idx];
    }
    if (tid < kOUT) Bl[tid] = fc_b[tid];

    const int lane = tid & 15;
    const int grp  = tid >> 4;
    const int node = blockIdx.x * 16 + grp;      // 0..2*kN-1, grid exact
    const int dir  = node >= kN;                 // 0: dst=movie, 1: dst=user
    const int d    = dir ? node - kN : node;
    const float* msgb = fu + (dir ? (size_t)kR * kN * kMPR : 0) + lane;
    const float* cip  = dir ? ci_user : ci_movie;
    float* outp       = dir ? out_u : out_m;

    uint32_t j  = starts[node * kR];
    const uint32_t je = starts[node * kR + kR];  // sentinel covers last node
    float a0 = 0.f, a1 = 0.f, a2 = 0.f, a3 = 0.f, a4 = 0.f;

    for (; j + 4 <= je; j += 4) {
        const uint32_t u0 = recs[j],     u1 = recs[j + 1];
        const uint32_t u2 = recs[j + 2], u3 = recs[j + 3];
        const float v0 = msgb[(size_t)(u0 & 0x7FFFFu) * kMPR];
        const float v1 = msgb[(size_t)(u1 & 0x7FFFFu) * kMPR];
        const float v2 = msgb[(size_t)(u2 & 0x7FFFFu) * kMPR];
        const float v3 = msgb[(size_t)(u3 & 0x7FFFFu) * kMPR];
        const uint32_t r0 = u0 >> 19, r1 = u1 >> 19, r2 = u2 >> 19, r3 = u3 >> 19;
        a0 += (r0 == 0u) ? v0 : 0.f; a1 += (r0 == 1u) ? v0 : 0.f;
        a2 += (r0 == 2u) ? v0 : 0.f; a3 += (r0 == 3u) ? v0 : 0.f;
        a4 += (r0 == 4u) ? v0 : 0.f;
        a0 += (r1 == 0u) ? v1 : 0.f; a1 += (r1 == 1u) ? v1 : 0.f;
        a2 += (r1 == 2u) ? v1 : 0.f; a3 += (r1 == 3u) ? v1 : 0.f;
        a4 += (r1 == 4u) ? v1 : 0.f;
        a0 += (r2 == 0u) ? v2 : 0.f; a1 += (r2 == 1u) ? v2 : 0.f;
        a2 += (r2 == 2u) ? v2 : 0.f; a3 += (r2 == 3u) ? v2 : 0.f;
        a4 += (r2 == 4u) ? v2 : 0.f;
        a0 += (r3 == 0u) ? v3 : 0.f; a1 += (r3 == 1u) ? v3 : 0.f;
        a2 += (r3 == 2u) ? v3 : 0.f; a3 += (r3 == 3u) ? v3 : 0.f;
        a4 += (r3 == 4u) ? v3 : 0.f;
    }
    for (; j < je; ++j) {
        const uint32_t u = recs[j];
        const float v = msgb[(size_t)(u & 0x7FFFFu) * kMPR];
        const uint32_t r = u >> 19;
        a0 += (r == 0u) ? v : 0.f; a1 += (r == 1u) ? v : 0.f;
        a2 += (r == 2u) ? v : 0.f; a3 += (r == 3u) ? v : 0.f;
        a4 += (r == 4u) ? v : 0.f;
    }

    const float c = cip[d];
    Xs[grp][0 * kMPR + lane] = fmaxf(a0 * c, 0.f);
    Xs[grp][1 * kMPR + lane] = fmaxf(a1 * c, 0.f);
    Xs[grp][2 * kMPR + lane] = fmaxf(a2 * c, 0.f);
    Xs[grp][3 * kMPR + lane] = fmaxf(a3 * c, 0.f);
    Xs[grp][4 * kMPR + lane] = fmaxf(a4 * c, 0.f);
    __syncthreads();                              // covers Wt/Bl preload too

    const float4* X4 = reinterpret_cast<const float4*>(&Xs[grp][0]);
    float4 a4v = reinterpret_cast<const float4*>(Bl)[lane];   // o = 4*lane..+3
#pragma unroll
    for (int jj = 0; jj < kMSG / 4; ++jj) {
        const float4 xv = X4[jj];                 // broadcast within group
        const float* Wr = &Wt[(jj * 4) * kOUT + lane * 4];
        const float4 w0 = *reinterpret_cast<const float4*>(Wr);
        const float4 w1 = *reinterpret_cast<const float4*>(Wr + kOUT);
        const float4 w2 = *reinterpret_cast<const float4*>(Wr + 2 * kOUT);
        const float4 w3 = *reinterpret_cast<const float4*>(Wr + 3 * kOUT);
        a4v.x += xv.x * w0.x + xv.y * w1.x + xv.z * w2.x + xv.w * w3.x;
        a4v.y += xv.x * w0.y + xv.y * w1.y + xv.z * w2.y + xv.w * w3.y;
        a4v.z += xv.x * w0.z + xv.y * w1.z + xv.z * w2.z + xv.w * w3.z;
        a4v.w += xv.x * w0.w + xv.y * w1.w + xv.z * w2.w + xv.w * w3.w;
    }
    *reinterpret_cast<float4*>(outp + (size_t)d * kOUT + lane * 4) = a4v;
}

// ---------------------------------------------------------------------------
extern "C" void kernel_launch(void* const* d_in, const int* in_sizes, int n_in,
                              void* d_out, int out_size, void* d_ws, size_t ws_size,
                              hipStream_t stream) {
    const float* ufeat    = (const float*)d_in[0];
    const float* ifeat    = (const float*)d_in[1];
    const float* cj_user  = (const float*)d_in[2];
    const float* ci_user  = (const float*)d_in[3];
    const float* cj_movie = (const float*)d_in[4];
    const float* ci_movie = (const float*)d_in[5];
    const int*   edge_user  = (const int*)d_in[6];
    const int*   edge_movie = (const int*)d_in[7];
    const float* att   = (const float*)d_in[8];
    const float* basis = (const float*)d_in[9];
    const float* fc_w  = (const float*)d_in[10];
    const float* fc_b  = (const float*)d_in[11];

    float* out_u = (float*)d_out;                    // [NU][64]
    float* out_m = out_u + (size_t)kNU * kOUT;       // [NM][64]

    // Workspace (108 MB):
    //   fu     [R][NU][16] f32 = 32 MB
    //   fi     [R][NM][16] f32 = 32 MB
    //   recs   [10M]       u32 = 40 MB   (sorted: plane_idx | r<<19)
    //   starts [1M+1]      u32 =  4 MB
    float* fu = (float*)d_ws;
    float* fi = fu + (size_t)kR * kN * kMPR;
    uint32_t* recs   = (uint32_t*)(fi + (size_t)kR * kN * kMPR);
    uint32_t* starts = recs + (size_t)kTotRecs;

    // Sort scratch lives in d_out (51.2 MB), fully overwritten by the final
    // gather: bucket_recs 40 MB + count/base/cursor (~4.7 KB).
    uint32_t* bucket_recs  = (uint32_t*)d_out;
    uint32_t* bucket_count = bucket_recs + (size_t)kTotRecs;
    uint32_t* bucket_base  = bucket_count + 2 * kNB;       // 2*kNB+1 entries
    uint32_t* cursorC      = bucket_base + 2 * kNB + 1;

    hipMemsetAsync(bucket_count, 0, (size_t)(2 * kNB) * sizeof(uint32_t), stream);

    gcmc_msg<<<(kN + 255) / 256, 256, 0, stream>>>(ufeat, cj_user,  att, basis, fu, kN);
    gcmc_msg<<<(kN + 255) / 256, 256, 0, stream>>>(ifeat, cj_movie, att, basis, fi, kN);

    // dir 0: user -> movie (dst = movie); dir 1: movie -> user (dst = user)
    gcmc_bucket_count<<<2 * kDirBlocks, 256, 0, stream>>>(
        edge_movie, edge_user, bucket_count);
    gcmc_bucket_scan<<<1, 512, 0, stream>>>(bucket_count, bucket_base, cursorC, starts);
    gcmc_partition<<<2 * kDirBlocks, 256, 0, stream>>>(
        edge_movie, edge_user, edge_user, edge_movie, cursorC, bucket_recs);
    gcmc_bucket_sort<<<2 * kNB, 256, 0, stream>>>(
        bucket_recs, bucket_base, starts, recs);

    gcmc_gather_fc<<<(2 * kN) / 16, 256, 0, stream>>>(
        fu, recs, starts, ci_user, ci_movie, fc_w, fc_b, out_u, out_m);
}